// Round 1
// baseline (772.048 us; speedup 1.0000x reference)
//
#include <hip/hip_runtime.h>

// EMD approx-match (auction) + match_cost, fused so the [B,N,M] match matrix
// is never materialized. Only O(B*N) state lives in d_ws:
//   remainL[B*N], remainR[B*M], rowscale[B*N], colcoef[B*M]
// Per level: 3 passes (row-normalize, col-clip, cost+rowupdate), each an
// N x M map-reduce recomputing exp(level*d2) from coordinates staged in LDS.

#define BATCH 8
#define NPTS 2048
#define MPTS 2048
#define BLOCK 256
#define ROWS 64  // rows (or cols) handled per block

// ---------------------------------------------------------------------------
__global__ __launch_bounds__(BLOCK) void emd_init_kernel(
    float* __restrict__ remainL, float* __restrict__ remainR,
    float* __restrict__ out) {
  int i = blockIdx.x * BLOCK + threadIdx.x;
  if (i < BATCH * NPTS) remainL[i] = 1.0f;  // multiL = 1 (N == M)
  if (i < BATCH * MPTS) remainR[i] = 1.0f;  // multiR = 1
  if (i < BATCH) out[i] = 0.0f;
}

// ---------------------------------------------------------------------------
// Pass A: rowscale[b,n] = remainL[b,n] / (sum_m exp(lvl*d2)*remainR[b,m] + 1e-9)
__global__ __launch_bounds__(BLOCK) void emd_passA_kernel(
    const float* __restrict__ xyz1, const float* __restrict__ xyz2,
    const float* __restrict__ remainL, const float* __restrict__ remainR,
    float* __restrict__ rowscale, float lvl) {
  __shared__ float4 sP[MPTS];       // (x2, y2, z2, ln(remainR))
  __shared__ float sRed[ROWS * 4];

  const int tid = threadIdx.x;
  const int bid = blockIdx.x;
  const int b = bid / (NPTS / ROWS);
  const int row0 = (bid % (NPTS / ROWS)) * ROWS;

  for (int m = tid; m < MPTS; m += BLOCK) {
    const float* p = xyz2 + ((size_t)b * MPTS + m) * 3;
    float w = remainR[b * MPTS + m];
    sP[m] = make_float4(p[0], p[1], p[2], __logf(w));  // ln(0) = -inf -> e=0
  }
  __syncthreads();

  const int wave = tid >> 6;      // m-quarter
  const int lane = tid & 63;
  const int phase = lane >> 4;    // m-phase within quarter
  const int rg = lane & 15;       // row group
  const int r0 = row0 + rg * 4;

  float x1[4], y1[4], z1[4];
#pragma unroll
  for (int j = 0; j < 4; ++j) {
    const float* p = xyz1 + ((size_t)b * NPTS + r0 + j) * 3;
    x1[j] = p[0]; y1[j] = p[1]; z1[j] = p[2];
  }
  float acc[4] = {0.f, 0.f, 0.f, 0.f};
  const int mb = wave * 512 + phase;
#pragma unroll 2
  for (int it = 0; it < 128; ++it) {
    float4 v = sP[mb + it * 4];
#pragma unroll
    for (int j = 0; j < 4; ++j) {
      float dx = x1[j] - v.x, dy = y1[j] - v.y, dz = z1[j] - v.z;
      float d2 = __builtin_fmaf(dx, dx, __builtin_fmaf(dy, dy, dz * dz));
      acc[j] += __expf(__builtin_fmaf(d2, lvl, v.w));  // exp(lvl*d2)*w
    }
  }
#pragma unroll
  for (int j = 0; j < 4; ++j) {
    acc[j] += __shfl_xor(acc[j], 16, 64);
    acc[j] += __shfl_xor(acc[j], 32, 64);
  }
  if (phase == 0) {
#pragma unroll
    for (int j = 0; j < 4; ++j) sRed[(rg * 4 + j) * 4 + wave] = acc[j];
  }
  __syncthreads();
  if (tid < ROWS) {
    float s = sRed[tid * 4] + sRed[tid * 4 + 1] + sRed[tid * 4 + 2] + sRed[tid * 4 + 3];
    size_t idx = (size_t)b * NPTS + row0 + tid;
    rowscale[idx] = remainL[idx] / (s + 1e-9f);
  }
}

// ---------------------------------------------------------------------------
// Pass B: per column m: t1 = sum_n exp(lvl*d2)*rs[n]; colsum = remainR*t1;
//         cs = min(remainR/(colsum+1e-9),1); colcoef = remainR*cs;
//         remainR = max(remainR - colsum*cs, 0)
__global__ __launch_bounds__(BLOCK) void emd_passB_kernel(
    const float* __restrict__ xyz1, const float* __restrict__ xyz2,
    const float* __restrict__ rowscale, float* __restrict__ remainR,
    float* __restrict__ colcoef, float lvl) {
  __shared__ float4 sP[NPTS];       // (x1, y1, z1, ln(rowscale))
  __shared__ float sRed[ROWS * 4];

  const int tid = threadIdx.x;
  const int bid = blockIdx.x;
  const int b = bid / (MPTS / ROWS);
  const int col0 = (bid % (MPTS / ROWS)) * ROWS;

  for (int n = tid; n < NPTS; n += BLOCK) {
    const float* p = xyz1 + ((size_t)b * NPTS + n) * 3;
    float rs = rowscale[b * NPTS + n];
    sP[n] = make_float4(p[0], p[1], p[2], __logf(rs));
  }
  __syncthreads();

  const int wave = tid >> 6;
  const int lane = tid & 63;
  const int phase = lane >> 4;
  const int cg = lane & 15;
  const int c0 = col0 + cg * 4;

  float x2[4], y2[4], z2[4];
#pragma unroll
  for (int j = 0; j < 4; ++j) {
    const float* p = xyz2 + ((size_t)b * MPTS + c0 + j) * 3;
    x2[j] = p[0]; y2[j] = p[1]; z2[j] = p[2];
  }
  float acc[4] = {0.f, 0.f, 0.f, 0.f};
  const int nb = wave * 512 + phase;
#pragma unroll 2
  for (int it = 0; it < 128; ++it) {
    float4 v = sP[nb + it * 4];
#pragma unroll
    for (int j = 0; j < 4; ++j) {
      float dx = x2[j] - v.x, dy = y2[j] - v.y, dz = z2[j] - v.z;
      float d2 = __builtin_fmaf(dx, dx, __builtin_fmaf(dy, dy, dz * dz));
      acc[j] += __expf(__builtin_fmaf(d2, lvl, v.w));  // exp(lvl*d2)*rs[n]
    }
  }
#pragma unroll
  for (int j = 0; j < 4; ++j) {
    acc[j] += __shfl_xor(acc[j], 16, 64);
    acc[j] += __shfl_xor(acc[j], 32, 64);
  }
  if (phase == 0) {
#pragma unroll
    for (int j = 0; j < 4; ++j) sRed[(cg * 4 + j) * 4 + wave] = acc[j];
  }
  __syncthreads();
  if (tid < ROWS) {
    float t1 = sRed[tid * 4] + sRed[tid * 4 + 1] + sRed[tid * 4 + 2] + sRed[tid * 4 + 3];
    size_t idx = (size_t)b * MPTS + col0 + tid;
    float rr = remainR[idx];
    float colsum = rr * t1;
    float cs = fminf(rr / (colsum + 1e-9f), 1.0f);
    colcoef[idx] = rr * cs;
    remainR[idx] = fmaxf(rr - colsum * cs, 0.0f);
  }
}

// ---------------------------------------------------------------------------
// Pass C: per row n: S2 = sum_m e*colcoef; C = sum_m e*colcoef*sqrt(d2);
//         remainL = max(remainL - rs*S2, 0); cost[b] += rs*C
__global__ __launch_bounds__(BLOCK) void emd_passC_kernel(
    const float* __restrict__ xyz1, const float* __restrict__ xyz2,
    const float* __restrict__ rowscale, float* __restrict__ remainL,
    const float* __restrict__ colcoef, float* __restrict__ out, float lvl) {
  __shared__ float4 sP[MPTS];       // (x2, y2, z2, ln(colcoef))
  __shared__ float sRedS[ROWS * 4];
  __shared__ float sRedC[ROWS * 4];
  __shared__ float sCost[ROWS];

  const int tid = threadIdx.x;
  const int bid = blockIdx.x;
  const int b = bid / (NPTS / ROWS);
  const int row0 = (bid % (NPTS / ROWS)) * ROWS;

  for (int m = tid; m < MPTS; m += BLOCK) {
    const float* p = xyz2 + ((size_t)b * MPTS + m) * 3;
    float cc = colcoef[b * MPTS + m];
    sP[m] = make_float4(p[0], p[1], p[2], __logf(cc));
  }
  __syncthreads();

  const int wave = tid >> 6;
  const int lane = tid & 63;
  const int phase = lane >> 4;
  const int rg = lane & 15;
  const int r0 = row0 + rg * 4;

  float x1[4], y1[4], z1[4];
#pragma unroll
  for (int j = 0; j < 4; ++j) {
    const float* p = xyz1 + ((size_t)b * NPTS + r0 + j) * 3;
    x1[j] = p[0]; y1[j] = p[1]; z1[j] = p[2];
  }
  float accS[4] = {0.f, 0.f, 0.f, 0.f};
  float accC[4] = {0.f, 0.f, 0.f, 0.f};
  const int mb = wave * 512 + phase;
#pragma unroll 2
  for (int it = 0; it < 128; ++it) {
    float4 v = sP[mb + it * 4];
#pragma unroll
    for (int j = 0; j < 4; ++j) {
      float dx = x1[j] - v.x, dy = y1[j] - v.y, dz = z1[j] - v.z;
      float d2 = __builtin_fmaf(dx, dx, __builtin_fmaf(dy, dy, dz * dz));
      float e = __expf(__builtin_fmaf(d2, lvl, v.w));  // exp(lvl*d2)*colcoef
      accS[j] += e;
      accC[j] += e * __builtin_sqrtf(d2);
    }
  }
#pragma unroll
  for (int j = 0; j < 4; ++j) {
    accS[j] += __shfl_xor(accS[j], 16, 64);
    accS[j] += __shfl_xor(accS[j], 32, 64);
    accC[j] += __shfl_xor(accC[j], 16, 64);
    accC[j] += __shfl_xor(accC[j], 32, 64);
  }
  if (phase == 0) {
#pragma unroll
    for (int j = 0; j < 4; ++j) {
      sRedS[(rg * 4 + j) * 4 + wave] = accS[j];
      sRedC[(rg * 4 + j) * 4 + wave] = accC[j];
    }
  }
  __syncthreads();
  if (tid < ROWS) {
    float S2 = sRedS[tid * 4] + sRedS[tid * 4 + 1] + sRedS[tid * 4 + 2] + sRedS[tid * 4 + 3];
    float C  = sRedC[tid * 4] + sRedC[tid * 4 + 1] + sRedC[tid * 4 + 2] + sRedC[tid * 4 + 3];
    size_t idx = (size_t)b * NPTS + row0 + tid;
    float rs = rowscale[idx];
    remainL[idx] = fmaxf(remainL[idx] - rs * S2, 0.0f);
    sCost[tid] = rs * C;
  }
  __syncthreads();
  if (tid == 0) {
    float t = 0.0f;
#pragma unroll
    for (int i = 0; i < ROWS; ++i) t += sCost[i];
    atomicAdd(out + b, t);
  }
}

// ---------------------------------------------------------------------------
extern "C" void kernel_launch(void* const* d_in, const int* in_sizes, int n_in,
                              void* d_out, int out_size, void* d_ws, size_t ws_size,
                              hipStream_t stream) {
  const float* xyz1 = (const float*)d_in[0];
  const float* xyz2 = (const float*)d_in[1];
  float* out = (float*)d_out;
  float* ws = (float*)d_ws;

  float* remainL  = ws;                                   // B*N
  float* remainR  = ws + BATCH * NPTS;                    // B*M
  float* rowscale = ws + BATCH * NPTS + BATCH * MPTS;     // B*N
  float* colcoef  = ws + 2 * BATCH * NPTS + BATCH * MPTS; // B*M

  emd_init_kernel<<<(BATCH * NPTS + BLOCK - 1) / BLOCK, BLOCK, 0, stream>>>(
      remainL, remainR, out);

  // j = 7..0 -> level = -4^j; j = -1 -> -0.25; j = -2 -> 0
  const float levels[10] = {-16384.f, -4096.f, -1024.f, -256.f, -64.f,
                            -16.f,    -4.f,    -1.f,    -0.25f, 0.f};
  dim3 grid(BATCH * (NPTS / ROWS));  // 256 blocks
  for (int l = 0; l < 10; ++l) {
    float lvl = levels[l];
    emd_passA_kernel<<<grid, BLOCK, 0, stream>>>(xyz1, xyz2, remainL, remainR,
                                                 rowscale, lvl);
    emd_passB_kernel<<<grid, BLOCK, 0, stream>>>(xyz1, xyz2, rowscale, remainR,
                                                 colcoef, lvl);
    emd_passC_kernel<<<grid, BLOCK, 0, stream>>>(xyz1, xyz2, rowscale, remainL,
                                                 colcoef, out, lvl);
  }
}

// Round 2
// 606.815 us; speedup vs baseline: 1.2723x; 1.2723x over previous
//
#include <hip/hip_runtime.h>

// EMD approx-match (auction) + match_cost, fused so the [B,N,M] match matrix
// is never materialized. Only O(B*N) state lives in d_ws:
//   remainL[B*N], remainR[B*M], rowscale[B*N], colcoef[B*M]
// Per level: 3 passes (row-normalize, col-clip, cost+rowupdate), each an
// N x M map-reduce recomputing exp(level*d2) from coordinates staged in LDS.
//
// R2: ROWS 64->16, grid 256->1024 blocks (4 blocks/CU, 4 waves/SIMD).
// R1 showed 1 block/CU (1 wave/SIMD) exposed the full ds_read->exp chain
// latency: ~25us/pass vs ~6us compute floor.

#define BATCH 8
#define NPTS 2048
#define MPTS 2048
#define BLOCK 256
#define ROWS 16  // rows (or cols) handled per block

// ---------------------------------------------------------------------------
__global__ __launch_bounds__(BLOCK) void emd_init_kernel(
    float* __restrict__ remainL, float* __restrict__ remainR,
    float* __restrict__ out) {
  int i = blockIdx.x * BLOCK + threadIdx.x;
  if (i < BATCH * NPTS) remainL[i] = 1.0f;  // multiL = 1 (N == M)
  if (i < BATCH * MPTS) remainR[i] = 1.0f;  // multiR = 1
  if (i < BATCH) out[i] = 0.0f;
}

// ---------------------------------------------------------------------------
// Pass A: rowscale[b,n] = remainL[b,n] / (sum_m exp(lvl*d2)*remainR[b,m] + 1e-9)
__global__ __launch_bounds__(BLOCK) void emd_passA_kernel(
    const float* __restrict__ xyz1, const float* __restrict__ xyz2,
    const float* __restrict__ remainL, const float* __restrict__ remainR,
    float* __restrict__ rowscale, float lvl) {
  __shared__ float4 sP[MPTS];       // (x2, y2, z2, ln(remainR))
  __shared__ float sRed[ROWS * 4];

  const int tid = threadIdx.x;
  const int bid = blockIdx.x;
  const int b = bid / (NPTS / ROWS);
  const int row0 = (bid % (NPTS / ROWS)) * ROWS;

  for (int m = tid; m < MPTS; m += BLOCK) {
    const float* p = xyz2 + ((size_t)b * MPTS + m) * 3;
    float w = remainR[b * MPTS + m];
    sP[m] = make_float4(p[0], p[1], p[2], __logf(w));  // ln(0) = -inf -> e=0
  }
  __syncthreads();

  const int wave = tid >> 6;      // m-quarter
  const int lane = tid & 63;
  const int phase = lane >> 2;    // 16 m-phases within quarter
  const int rg = lane & 3;        // 4 row groups
  const int r0 = row0 + rg * 4;

  float x1[4], y1[4], z1[4];
#pragma unroll
  for (int j = 0; j < 4; ++j) {
    const float* p = xyz1 + ((size_t)b * NPTS + r0 + j) * 3;
    x1[j] = p[0]; y1[j] = p[1]; z1[j] = p[2];
  }
  float acc[4] = {0.f, 0.f, 0.f, 0.f};
  const int mb = wave * 512 + phase;
#pragma unroll 4
  for (int it = 0; it < 32; ++it) {
    float4 v = sP[mb + it * 16];
#pragma unroll
    for (int j = 0; j < 4; ++j) {
      float dx = x1[j] - v.x, dy = y1[j] - v.y, dz = z1[j] - v.z;
      float d2 = __builtin_fmaf(dx, dx, __builtin_fmaf(dy, dy, dz * dz));
      acc[j] += __expf(__builtin_fmaf(d2, lvl, v.w));  // exp(lvl*d2)*w
    }
  }
#pragma unroll
  for (int j = 0; j < 4; ++j) {
    acc[j] += __shfl_xor(acc[j], 4, 64);
    acc[j] += __shfl_xor(acc[j], 8, 64);
    acc[j] += __shfl_xor(acc[j], 16, 64);
    acc[j] += __shfl_xor(acc[j], 32, 64);
  }
  if (phase == 0) {
#pragma unroll
    for (int j = 0; j < 4; ++j) sRed[(rg * 4 + j) * 4 + wave] = acc[j];
  }
  __syncthreads();
  if (tid < ROWS) {
    float s = sRed[tid * 4] + sRed[tid * 4 + 1] + sRed[tid * 4 + 2] + sRed[tid * 4 + 3];
    size_t idx = (size_t)b * NPTS + row0 + tid;
    rowscale[idx] = remainL[idx] / (s + 1e-9f);
  }
}

// ---------------------------------------------------------------------------
// Pass B: per column m: t1 = sum_n exp(lvl*d2)*rs[n]; colsum = remainR*t1;
//         cs = min(remainR/(colsum+1e-9),1); colcoef = remainR*cs;
//         remainR = max(remainR - colsum*cs, 0)
__global__ __launch_bounds__(BLOCK) void emd_passB_kernel(
    const float* __restrict__ xyz1, const float* __restrict__ xyz2,
    const float* __restrict__ rowscale, float* __restrict__ remainR,
    float* __restrict__ colcoef, float lvl) {
  __shared__ float4 sP[NPTS];       // (x1, y1, z1, ln(rowscale))
  __shared__ float sRed[ROWS * 4];

  const int tid = threadIdx.x;
  const int bid = blockIdx.x;
  const int b = bid / (MPTS / ROWS);
  const int col0 = (bid % (MPTS / ROWS)) * ROWS;

  for (int n = tid; n < NPTS; n += BLOCK) {
    const float* p = xyz1 + ((size_t)b * NPTS + n) * 3;
    float rs = rowscale[b * NPTS + n];
    sP[n] = make_float4(p[0], p[1], p[2], __logf(rs));
  }
  __syncthreads();

  const int wave = tid >> 6;
  const int lane = tid & 63;
  const int phase = lane >> 2;
  const int cg = lane & 3;
  const int c0 = col0 + cg * 4;

  float x2[4], y2[4], z2[4];
#pragma unroll
  for (int j = 0; j < 4; ++j) {
    const float* p = xyz2 + ((size_t)b * MPTS + c0 + j) * 3;
    x2[j] = p[0]; y2[j] = p[1]; z2[j] = p[2];
  }
  float acc[4] = {0.f, 0.f, 0.f, 0.f};
  const int nb = wave * 512 + phase;
#pragma unroll 4
  for (int it = 0; it < 32; ++it) {
    float4 v = sP[nb + it * 16];
#pragma unroll
    for (int j = 0; j < 4; ++j) {
      float dx = x2[j] - v.x, dy = y2[j] - v.y, dz = z2[j] - v.z;
      float d2 = __builtin_fmaf(dx, dx, __builtin_fmaf(dy, dy, dz * dz));
      acc[j] += __expf(__builtin_fmaf(d2, lvl, v.w));  // exp(lvl*d2)*rs[n]
    }
  }
#pragma unroll
  for (int j = 0; j < 4; ++j) {
    acc[j] += __shfl_xor(acc[j], 4, 64);
    acc[j] += __shfl_xor(acc[j], 8, 64);
    acc[j] += __shfl_xor(acc[j], 16, 64);
    acc[j] += __shfl_xor(acc[j], 32, 64);
  }
  if (phase == 0) {
#pragma unroll
    for (int j = 0; j < 4; ++j) sRed[(cg * 4 + j) * 4 + wave] = acc[j];
  }
  __syncthreads();
  if (tid < ROWS) {
    float t1 = sRed[tid * 4] + sRed[tid * 4 + 1] + sRed[tid * 4 + 2] + sRed[tid * 4 + 3];
    size_t idx = (size_t)b * MPTS + col0 + tid;
    float rr = remainR[idx];
    float colsum = rr * t1;
    float cs = fminf(rr / (colsum + 1e-9f), 1.0f);
    colcoef[idx] = rr * cs;
    remainR[idx] = fmaxf(rr - colsum * cs, 0.0f);
  }
}

// ---------------------------------------------------------------------------
// Pass C: per row n: S2 = sum_m e*colcoef; C = sum_m e*colcoef*sqrt(d2);
//         remainL = max(remainL - rs*S2, 0); cost[b] += rs*C
__global__ __launch_bounds__(BLOCK) void emd_passC_kernel(
    const float* __restrict__ xyz1, const float* __restrict__ xyz2,
    const float* __restrict__ rowscale, float* __restrict__ remainL,
    const float* __restrict__ colcoef, float* __restrict__ out, float lvl) {
  __shared__ float4 sP[MPTS];       // (x2, y2, z2, ln(colcoef))
  __shared__ float sRedS[ROWS * 4];
  __shared__ float sRedC[ROWS * 4];
  __shared__ float sCost[ROWS];

  const int tid = threadIdx.x;
  const int bid = blockIdx.x;
  const int b = bid / (NPTS / ROWS);
  const int row0 = (bid % (NPTS / ROWS)) * ROWS;

  for (int m = tid; m < MPTS; m += BLOCK) {
    const float* p = xyz2 + ((size_t)b * MPTS + m) * 3;
    float cc = colcoef[b * MPTS + m];
    sP[m] = make_float4(p[0], p[1], p[2], __logf(cc));
  }
  __syncthreads();

  const int wave = tid >> 6;
  const int lane = tid & 63;
  const int phase = lane >> 2;
  const int rg = lane & 3;
  const int r0 = row0 + rg * 4;

  float x1[4], y1[4], z1[4];
#pragma unroll
  for (int j = 0; j < 4; ++j) {
    const float* p = xyz1 + ((size_t)b * NPTS + r0 + j) * 3;
    x1[j] = p[0]; y1[j] = p[1]; z1[j] = p[2];
  }
  float accS[4] = {0.f, 0.f, 0.f, 0.f};
  float accC[4] = {0.f, 0.f, 0.f, 0.f};
  const int mb = wave * 512 + phase;
#pragma unroll 4
  for (int it = 0; it < 32; ++it) {
    float4 v = sP[mb + it * 16];
#pragma unroll
    for (int j = 0; j < 4; ++j) {
      float dx = x1[j] - v.x, dy = y1[j] - v.y, dz = z1[j] - v.z;
      float d2 = __builtin_fmaf(dx, dx, __builtin_fmaf(dy, dy, dz * dz));
      float e = __expf(__builtin_fmaf(d2, lvl, v.w));  // exp(lvl*d2)*colcoef
      accS[j] += e;
      accC[j] += e * __builtin_sqrtf(d2);
    }
  }
#pragma unroll
  for (int j = 0; j < 4; ++j) {
    accS[j] += __shfl_xor(accS[j], 4, 64);
    accS[j] += __shfl_xor(accS[j], 8, 64);
    accS[j] += __shfl_xor(accS[j], 16, 64);
    accS[j] += __shfl_xor(accS[j], 32, 64);
    accC[j] += __shfl_xor(accC[j], 4, 64);
    accC[j] += __shfl_xor(accC[j], 8, 64);
    accC[j] += __shfl_xor(accC[j], 16, 64);
    accC[j] += __shfl_xor(accC[j], 32, 64);
  }
  if (phase == 0) {
#pragma unroll
    for (int j = 0; j < 4; ++j) {
      sRedS[(rg * 4 + j) * 4 + wave] = accS[j];
      sRedC[(rg * 4 + j) * 4 + wave] = accC[j];
    }
  }
  __syncthreads();
  if (tid < ROWS) {
    float S2 = sRedS[tid * 4] + sRedS[tid * 4 + 1] + sRedS[tid * 4 + 2] + sRedS[tid * 4 + 3];
    float C  = sRedC[tid * 4] + sRedC[tid * 4 + 1] + sRedC[tid * 4 + 2] + sRedC[tid * 4 + 3];
    size_t idx = (size_t)b * NPTS + row0 + tid;
    float rs = rowscale[idx];
    remainL[idx] = fmaxf(remainL[idx] - rs * S2, 0.0f);
    sCost[tid] = rs * C;
  }
  __syncthreads();
  if (tid == 0) {
    float t = 0.0f;
#pragma unroll
    for (int i = 0; i < ROWS; ++i) t += sCost[i];
    atomicAdd(out + b, t);
  }
}

// ---------------------------------------------------------------------------
extern "C" void kernel_launch(void* const* d_in, const int* in_sizes, int n_in,
                              void* d_out, int out_size, void* d_ws, size_t ws_size,
                              hipStream_t stream) {
  const float* xyz1 = (const float*)d_in[0];
  const float* xyz2 = (const float*)d_in[1];
  float* out = (float*)d_out;
  float* ws = (float*)d_ws;

  float* remainL  = ws;                                   // B*N
  float* remainR  = ws + BATCH * NPTS;                    // B*M
  float* rowscale = ws + BATCH * NPTS + BATCH * MPTS;     // B*N
  float* colcoef  = ws + 2 * BATCH * NPTS + BATCH * MPTS; // B*M

  emd_init_kernel<<<(BATCH * NPTS + BLOCK - 1) / BLOCK, BLOCK, 0, stream>>>(
      remainL, remainR, out);

  // j = 7..0 -> level = -4^j; j = -1 -> -0.25; j = -2 -> 0
  const float levels[10] = {-16384.f, -4096.f, -1024.f, -256.f, -64.f,
                            -16.f,    -4.f,    -1.f,    -0.25f, 0.f};
  dim3 grid(BATCH * (NPTS / ROWS));  // 1024 blocks = 4 blocks/CU
  for (int l = 0; l < 10; ++l) {
    float lvl = levels[l];
    emd_passA_kernel<<<grid, BLOCK, 0, stream>>>(xyz1, xyz2, remainL, remainR,
                                                 rowscale, lvl);
    emd_passB_kernel<<<grid, BLOCK, 0, stream>>>(xyz1, xyz2, rowscale, remainR,
                                                 colcoef, lvl);
    emd_passC_kernel<<<grid, BLOCK, 0, stream>>>(xyz1, xyz2, rowscale, remainL,
                                                 colcoef, out, lvl);
  }
}

// Round 3
// 522.846 us; speedup vs baseline: 1.4766x; 1.1606x over previous
//
#include <hip/hip_runtime.h>
#include <hip/hip_fp16.h>

// EMD approx-match (auction) + match_cost, fused: the [B,N,M] match matrix is
// never materialized. O(B*N) state in d_ws: remainL, remainR, rowscale, colcoef.
//
// R3 structure (21 kernels instead of 31):
//   A0               rowscale(0) from remainL=remainR=1        [row pass]
//   B(l) l=0..8      col-clip -> colcoef, remainR update       [col pass]
//   CA(l) l=0..8     cost(l) + remainL update + rowscale(l+1)  [row pass, shares d2]
//   B9sp             lvl=0 => colsum = rr * sum(rs): tiny 8-block kernel
//   C9sp             lvl=0 => cost += rs * sum(cc*sqrt(d2)), no exp
// CA stages (x,y,z, half2(colcoef, remainR)) -> 32 KB LDS, 4 blocks/CU.

#define BATCH 8
#define NPTS 2048
#define MPTS 2048
#define BLOCK 256
#define ROWS 16

// ---------------------------------------------------------------------------
// A0: rowscale[b,n] = 1 / (sum_m exp(lvl*d2) + 1e-9)   (remainL=remainR=1)
// Also zeroes out[] (block 0).
__global__ __launch_bounds__(BLOCK) void emd_A0_kernel(
    const float* __restrict__ xyz1, const float* __restrict__ xyz2,
    float* __restrict__ rowscale, float* __restrict__ out, float lvl) {
  __shared__ float4 sP[MPTS];
  __shared__ float sRed[ROWS * 4];

  const int tid = threadIdx.x;
  const int bid = blockIdx.x;
  const int b = bid / (NPTS / ROWS);
  const int row0 = (bid % (NPTS / ROWS)) * ROWS;

  if (bid == 0 && tid < BATCH) out[tid] = 0.0f;

  for (int m = tid; m < MPTS; m += BLOCK) {
    const float* p = xyz2 + ((size_t)b * MPTS + m) * 3;
    sP[m] = make_float4(p[0], p[1], p[2], 0.0f);
  }
  __syncthreads();

  const int wave = tid >> 6;
  const int lane = tid & 63;
  const int phase = lane >> 2;
  const int rg = lane & 3;
  const int r0 = row0 + rg * 4;

  float x1[4], y1[4], z1[4];
#pragma unroll
  for (int j = 0; j < 4; ++j) {
    const float* p = xyz1 + ((size_t)b * NPTS + r0 + j) * 3;
    x1[j] = p[0]; y1[j] = p[1]; z1[j] = p[2];
  }
  float acc[4] = {0.f, 0.f, 0.f, 0.f};
  const int mb = wave * 512 + phase;
#pragma unroll 4
  for (int it = 0; it < 32; ++it) {
    float4 v = sP[mb + it * 16];
#pragma unroll
    for (int j = 0; j < 4; ++j) {
      float dx = x1[j] - v.x, dy = y1[j] - v.y, dz = z1[j] - v.z;
      float d2 = __builtin_fmaf(dx, dx, __builtin_fmaf(dy, dy, dz * dz));
      acc[j] += __expf(lvl * d2);
    }
  }
#pragma unroll
  for (int j = 0; j < 4; ++j) {
    acc[j] += __shfl_xor(acc[j], 4, 64);
    acc[j] += __shfl_xor(acc[j], 8, 64);
    acc[j] += __shfl_xor(acc[j], 16, 64);
    acc[j] += __shfl_xor(acc[j], 32, 64);
  }
  if (phase == 0) {
#pragma unroll
    for (int j = 0; j < 4; ++j) sRed[(rg * 4 + j) * 4 + wave] = acc[j];
  }
  __syncthreads();
  if (tid < ROWS) {
    float s = sRed[tid * 4] + sRed[tid * 4 + 1] + sRed[tid * 4 + 2] + sRed[tid * 4 + 3];
    rowscale[(size_t)b * NPTS + row0 + tid] = 1.0f / (s + 1e-9f);
  }
}

// ---------------------------------------------------------------------------
// B(l): per column m: t1 = sum_n exp(lvl*d2)*rs[n]; colsum = rr*t1;
//       cs = min(rr/(colsum+1e-9),1); colcoef = rr*cs; rr = max(rr-colsum*cs,0)
// FIRST: rr == 1 (no remainR read).
template <bool FIRST>
__global__ __launch_bounds__(BLOCK) void emd_B_kernel(
    const float* __restrict__ xyz1, const float* __restrict__ xyz2,
    const float* __restrict__ rowscale, float* __restrict__ remainR,
    float* __restrict__ colcoef, float lvl) {
  __shared__ float4 sP[NPTS];   // (x1,y1,z1, rowscale)
  __shared__ float sRed[ROWS * 4];

  const int tid = threadIdx.x;
  const int bid = blockIdx.x;
  const int b = bid / (MPTS / ROWS);
  const int col0 = (bid % (MPTS / ROWS)) * ROWS;

  for (int n = tid; n < NPTS; n += BLOCK) {
    const float* p = xyz1 + ((size_t)b * NPTS + n) * 3;
    sP[n] = make_float4(p[0], p[1], p[2], rowscale[b * NPTS + n]);
  }
  __syncthreads();

  const int wave = tid >> 6;
  const int lane = tid & 63;
  const int phase = lane >> 2;
  const int cg = lane & 3;
  const int c0 = col0 + cg * 4;

  float x2[4], y2[4], z2[4];
#pragma unroll
  for (int j = 0; j < 4; ++j) {
    const float* p = xyz2 + ((size_t)b * MPTS + c0 + j) * 3;
    x2[j] = p[0]; y2[j] = p[1]; z2[j] = p[2];
  }
  float acc[4] = {0.f, 0.f, 0.f, 0.f};
  const int nb = wave * 512 + phase;
#pragma unroll 4
  for (int it = 0; it < 32; ++it) {
    float4 v = sP[nb + it * 16];
#pragma unroll
    for (int j = 0; j < 4; ++j) {
      float dx = x2[j] - v.x, dy = y2[j] - v.y, dz = z2[j] - v.z;
      float d2 = __builtin_fmaf(dx, dx, __builtin_fmaf(dy, dy, dz * dz));
      acc[j] = __builtin_fmaf(__expf(lvl * d2), v.w, acc[j]);
    }
  }
#pragma unroll
  for (int j = 0; j < 4; ++j) {
    acc[j] += __shfl_xor(acc[j], 4, 64);
    acc[j] += __shfl_xor(acc[j], 8, 64);
    acc[j] += __shfl_xor(acc[j], 16, 64);
    acc[j] += __shfl_xor(acc[j], 32, 64);
  }
  if (phase == 0) {
#pragma unroll
    for (int j = 0; j < 4; ++j) sRed[(cg * 4 + j) * 4 + wave] = acc[j];
  }
  __syncthreads();
  if (tid < ROWS) {
    float t1 = sRed[tid * 4] + sRed[tid * 4 + 1] + sRed[tid * 4 + 2] + sRed[tid * 4 + 3];
    size_t idx = (size_t)b * MPTS + col0 + tid;
    float rr = FIRST ? 1.0f : remainR[idx];
    float colsum = rr * t1;
    float cs = fminf(rr / (colsum + 1e-9f), 1.0f);
    colcoef[idx] = rr * cs;
    remainR[idx] = fmaxf(rr - colsum * cs, 0.0f);
  }
}

// ---------------------------------------------------------------------------
// CA(l): fused passC(level l) + passA(level l+1). Row pass.
//  C: S2 = sum_m e1*cc; C = sum_m e1*cc*sqrt(d2)  with e1 = exp(lvlC*d2)
//  A: R  = sum_m e2*rr                            with e2 = exp(lvlA*d2)
//  remainL = max(remainL - rs*S2, 0); cost[b] += rs*C; rowscale = remainL/(R+1e-9)
// Weights (cc, rr) staged as half2 in sP[].w.
template <bool FIRST>
__global__ __launch_bounds__(BLOCK) void emd_CA_kernel(
    const float* __restrict__ xyz1, const float* __restrict__ xyz2,
    float* __restrict__ rowscale, float* __restrict__ remainL,
    const float* __restrict__ remainR, const float* __restrict__ colcoef,
    float* __restrict__ out, float lvlC, float lvlA) {
  __shared__ float4 sP[MPTS];   // (x2,y2,z2, half2(cc, rr))
  __shared__ float sRedS[ROWS * 4];
  __shared__ float sRedC[ROWS * 4];
  __shared__ float sRedR[ROWS * 4];
  __shared__ float sCost[ROWS];

  const int tid = threadIdx.x;
  const int bid = blockIdx.x;
  const int b = bid / (NPTS / ROWS);
  const int row0 = (bid % (NPTS / ROWS)) * ROWS;

  for (int m = tid; m < MPTS; m += BLOCK) {
    const float* p = xyz2 + ((size_t)b * MPTS + m) * 3;
    size_t idx = (size_t)b * MPTS + m;
    __half2 h = __halves2half2(__float2half_rn(colcoef[idx]),
                               __float2half_rn(remainR[idx]));
    sP[m] = make_float4(p[0], p[1], p[2], __builtin_bit_cast(float, h));
  }
  __syncthreads();

  const int wave = tid >> 6;
  const int lane = tid & 63;
  const int phase = lane >> 2;
  const int rg = lane & 3;
  const int r0 = row0 + rg * 4;

  float x1[4], y1[4], z1[4];
#pragma unroll
  for (int j = 0; j < 4; ++j) {
    const float* p = xyz1 + ((size_t)b * NPTS + r0 + j) * 3;
    x1[j] = p[0]; y1[j] = p[1]; z1[j] = p[2];
  }
  float accS[4] = {0.f, 0.f, 0.f, 0.f};
  float accC[4] = {0.f, 0.f, 0.f, 0.f};
  float accR[4] = {0.f, 0.f, 0.f, 0.f};
  const int mb = wave * 512 + phase;
#pragma unroll 4
  for (int it = 0; it < 32; ++it) {
    float4 v = sP[mb + it * 16];
    __half2 h = __builtin_bit_cast(__half2, v.w);
    float cc = __low2float(h);
    float rr = __high2float(h);
#pragma unroll
    for (int j = 0; j < 4; ++j) {
      float dx = x1[j] - v.x, dy = y1[j] - v.y, dz = z1[j] - v.z;
      float d2 = __builtin_fmaf(dx, dx, __builtin_fmaf(dy, dy, dz * dz));
      float sq = __builtin_sqrtf(d2);
      float e1 = __expf(lvlC * d2);
      float e2 = __expf(lvlA * d2);
      float t = e1 * cc;
      accS[j] += t;
      accC[j] = __builtin_fmaf(t, sq, accC[j]);
      accR[j] = __builtin_fmaf(e2, rr, accR[j]);
    }
  }
#pragma unroll
  for (int j = 0; j < 4; ++j) {
    accS[j] += __shfl_xor(accS[j], 4, 64);
    accS[j] += __shfl_xor(accS[j], 8, 64);
    accS[j] += __shfl_xor(accS[j], 16, 64);
    accS[j] += __shfl_xor(accS[j], 32, 64);
    accC[j] += __shfl_xor(accC[j], 4, 64);
    accC[j] += __shfl_xor(accC[j], 8, 64);
    accC[j] += __shfl_xor(accC[j], 16, 64);
    accC[j] += __shfl_xor(accC[j], 32, 64);
    accR[j] += __shfl_xor(accR[j], 4, 64);
    accR[j] += __shfl_xor(accR[j], 8, 64);
    accR[j] += __shfl_xor(accR[j], 16, 64);
    accR[j] += __shfl_xor(accR[j], 32, 64);
  }
  if (phase == 0) {
#pragma unroll
    for (int j = 0; j < 4; ++j) {
      sRedS[(rg * 4 + j) * 4 + wave] = accS[j];
      sRedC[(rg * 4 + j) * 4 + wave] = accC[j];
      sRedR[(rg * 4 + j) * 4 + wave] = accR[j];
    }
  }
  __syncthreads();
  if (tid < ROWS) {
    float S2 = sRedS[tid * 4] + sRedS[tid * 4 + 1] + sRedS[tid * 4 + 2] + sRedS[tid * 4 + 3];
    float C  = sRedC[tid * 4] + sRedC[tid * 4 + 1] + sRedC[tid * 4 + 2] + sRedC[tid * 4 + 3];
    float R  = sRedR[tid * 4] + sRedR[tid * 4 + 1] + sRedR[tid * 4 + 2] + sRedR[tid * 4 + 3];
    size_t idx = (size_t)b * NPTS + row0 + tid;
    float rs = rowscale[idx];
    float rl = FIRST ? 1.0f : remainL[idx];
    float rlN = fmaxf(rl - rs * S2, 0.0f);
    remainL[idx] = rlN;
    rowscale[idx] = rlN / (R + 1e-9f);   // next level's rowscale
    sCost[tid] = rs * C;
  }
  __syncthreads();
  if (tid == 0) {
    float t = 0.0f;
#pragma unroll
    for (int i = 0; i < ROWS; ++i) t += sCost[i];
    atomicAdd(out + b, t);
  }
}

// ---------------------------------------------------------------------------
// B9sp (lvl=0): t1 = sum_n rs[n] per batch; colcoef = rr*min(rr/(rr*t1+1e-9),1)
// One block per batch. remainR is dead afterwards (not updated).
__global__ __launch_bounds__(BLOCK) void emd_B9_kernel(
    const float* __restrict__ rowscale, const float* __restrict__ remainR,
    float* __restrict__ colcoef) {
  __shared__ float sW[4];
  const int tid = threadIdx.x;
  const int b = blockIdx.x;
  float s = 0.0f;
#pragma unroll
  for (int k = 0; k < NPTS / BLOCK; ++k)
    s += rowscale[(size_t)b * NPTS + tid + k * BLOCK];
  s += __shfl_xor(s, 1, 64);  s += __shfl_xor(s, 2, 64);
  s += __shfl_xor(s, 4, 64);  s += __shfl_xor(s, 8, 64);
  s += __shfl_xor(s, 16, 64); s += __shfl_xor(s, 32, 64);
  if ((tid & 63) == 0) sW[tid >> 6] = s;
  __syncthreads();
  float t1 = sW[0] + sW[1] + sW[2] + sW[3];
  for (int m = tid; m < MPTS; m += BLOCK) {
    size_t idx = (size_t)b * MPTS + m;
    float rr = remainR[idx];
    float colsum = rr * t1;
    float cs = fminf(rr / (colsum + 1e-9f), 1.0f);
    colcoef[idx] = rr * cs;
  }
}

// ---------------------------------------------------------------------------
// C9sp (lvl=0): cost[b] += rs[n] * sum_m cc[m]*sqrt(d2). No exp, no updates.
__global__ __launch_bounds__(BLOCK) void emd_C9_kernel(
    const float* __restrict__ xyz1, const float* __restrict__ xyz2,
    const float* __restrict__ rowscale, const float* __restrict__ colcoef,
    float* __restrict__ out) {
  __shared__ float4 sP[MPTS];   // (x2,y2,z2, colcoef)
  __shared__ float sRed[ROWS * 4];
  __shared__ float sCost[ROWS];

  const int tid = threadIdx.x;
  const int bid = blockIdx.x;
  const int b = bid / (NPTS / ROWS);
  const int row0 = (bid % (NPTS / ROWS)) * ROWS;

  for (int m = tid; m < MPTS; m += BLOCK) {
    const float* p = xyz2 + ((size_t)b * MPTS + m) * 3;
    sP[m] = make_float4(p[0], p[1], p[2], colcoef[(size_t)b * MPTS + m]);
  }
  __syncthreads();

  const int wave = tid >> 6;
  const int lane = tid & 63;
  const int phase = lane >> 2;
  const int rg = lane & 3;
  const int r0 = row0 + rg * 4;

  float x1[4], y1[4], z1[4];
#pragma unroll
  for (int j = 0; j < 4; ++j) {
    const float* p = xyz1 + ((size_t)b * NPTS + r0 + j) * 3;
    x1[j] = p[0]; y1[j] = p[1]; z1[j] = p[2];
  }
  float acc[4] = {0.f, 0.f, 0.f, 0.f};
  const int mb = wave * 512 + phase;
#pragma unroll 4
  for (int it = 0; it < 32; ++it) {
    float4 v = sP[mb + it * 16];
#pragma unroll
    for (int j = 0; j < 4; ++j) {
      float dx = x1[j] - v.x, dy = y1[j] - v.y, dz = z1[j] - v.z;
      float d2 = __builtin_fmaf(dx, dx, __builtin_fmaf(dy, dy, dz * dz));
      acc[j] = __builtin_fmaf(__builtin_sqrtf(d2), v.w, acc[j]);
    }
  }
#pragma unroll
  for (int j = 0; j < 4; ++j) {
    acc[j] += __shfl_xor(acc[j], 4, 64);
    acc[j] += __shfl_xor(acc[j], 8, 64);
    acc[j] += __shfl_xor(acc[j], 16, 64);
    acc[j] += __shfl_xor(acc[j], 32, 64);
  }
  if (phase == 0) {
#pragma unroll
    for (int j = 0; j < 4; ++j) sRed[(rg * 4 + j) * 4 + wave] = acc[j];
  }
  __syncthreads();
  if (tid < ROWS) {
    float C = sRed[tid * 4] + sRed[tid * 4 + 1] + sRed[tid * 4 + 2] + sRed[tid * 4 + 3];
    sCost[tid] = rowscale[(size_t)b * NPTS + row0 + tid] * C;
  }
  __syncthreads();
  if (tid == 0) {
    float t = 0.0f;
#pragma unroll
    for (int i = 0; i < ROWS; ++i) t += sCost[i];
    atomicAdd(out + b, t);
  }
}

// ---------------------------------------------------------------------------
extern "C" void kernel_launch(void* const* d_in, const int* in_sizes, int n_in,
                              void* d_out, int out_size, void* d_ws, size_t ws_size,
                              hipStream_t stream) {
  const float* xyz1 = (const float*)d_in[0];
  const float* xyz2 = (const float*)d_in[1];
  float* out = (float*)d_out;
  float* ws = (float*)d_ws;

  float* remainL  = ws;                                   // B*N
  float* remainR  = ws + BATCH * NPTS;                    // B*M
  float* rowscale = ws + BATCH * NPTS + BATCH * MPTS;     // B*N
  float* colcoef  = ws + 2 * BATCH * NPTS + BATCH * MPTS; // B*M

  // j = 7..0 -> level = -4^j; j = -1 -> -0.25; j = -2 -> 0
  const float levels[10] = {-16384.f, -4096.f, -1024.f, -256.f, -64.f,
                            -16.f,    -4.f,    -1.f,    -0.25f, 0.f};
  dim3 grid(BATCH * (NPTS / ROWS));  // 1024 blocks

  emd_A0_kernel<<<grid, BLOCK, 0, stream>>>(xyz1, xyz2, rowscale, out, levels[0]);
  emd_B_kernel<true><<<grid, BLOCK, 0, stream>>>(xyz1, xyz2, rowscale, remainR,
                                                 colcoef, levels[0]);
  emd_CA_kernel<true><<<grid, BLOCK, 0, stream>>>(xyz1, xyz2, rowscale, remainL,
                                                  remainR, colcoef, out,
                                                  levels[0], levels[1]);
  for (int l = 1; l <= 8; ++l) {
    emd_B_kernel<false><<<grid, BLOCK, 0, stream>>>(xyz1, xyz2, rowscale, remainR,
                                                    colcoef, levels[l]);
    emd_CA_kernel<false><<<grid, BLOCK, 0, stream>>>(xyz1, xyz2, rowscale, remainL,
                                                     remainR, colcoef, out,
                                                     levels[l], levels[l + 1]);
  }
  emd_B9_kernel<<<BATCH, BLOCK, 0, stream>>>(rowscale, remainR, colcoef);
  emd_C9_kernel<<<grid, BLOCK, 0, stream>>>(xyz1, xyz2, rowscale, colcoef, out);
}